// Round 1
// baseline (10499.489 us; speedup 1.0000x reference)
//
#include <hip/hip_runtime.h>
#include <math.h>

#define BN_EPS 1e-5f
constexpr int Bc = 8, Nc = 8192, Sc = 1024, CINc = 64;

// ---------------- xyz transpose + |p|^2 ----------------
__global__ __launch_bounds__(256) void xyzt_kernel(const float* __restrict__ xyz,
                                                   float4* __restrict__ xyzT) {
  int i = blockIdx.x * 256 + threadIdx.x;
  if (i >= Bc * Nc) return;
  int b = i / Nc, n = i % Nc;
  const float* xb = xyz + (size_t)b * 3 * Nc;
  float x = xb[n], y = xb[Nc + n], z = xb[2 * Nc + n];
  xyzT[i] = make_float4(x, y, z, fmaf(z, z, fmaf(y, y, x * x)));
}

// ---------------- farthest point sampling ----------------
__global__ __launch_bounds__(512) void fps_kernel(const float* __restrict__ xyz,
                                                  float4* __restrict__ newxyz,
                                                  float* __restrict__ out0) {
  int b = blockIdx.x, t = threadIdx.x;
  const float* xb = xyz + (size_t)b * 3 * Nc;
  float px[16], py[16], pz[16], dd[16];
#pragma unroll
  for (int j = 0; j < 16; j++) {
    int n = j * 512 + t;
    px[j] = xb[n];
    py[j] = xb[Nc + n];
    pz[j] = xb[2 * Nc + n];
    dd[j] = 1e10f;
  }
  __shared__ float cs[3];
  __shared__ unsigned long long red[8];
  if (t == 0) { cs[0] = xb[0]; cs[1] = xb[Nc]; cs[2] = xb[2 * Nc]; }
  __syncthreads();
  for (int i = 0; i < Sc; i++) {
    float cx = cs[0], cy = cs[1], cz = cs[2];
    if (t == 0) {
      newxyz[b * Sc + i] = make_float4(cx, cy, cz, fmaf(cz, cz, fmaf(cy, cy, cx * cx)));
      float* ob = out0 + (size_t)b * 3 * Sc;
      ob[i] = cx; ob[Sc + i] = cy; ob[2 * Sc + i] = cz;
    }
    float bd = -1.f;
    int bnidx = 0;
#pragma unroll
    for (int j = 0; j < 16; j++) {
      float dx = px[j] - cx, dy = py[j] - cy, dz = pz[j] - cz;
      float d = fmaf(dz, dz, fmaf(dy, dy, dx * dx));
      d = fminf(dd[j], d);
      dd[j] = d;
      if (d > bd) { bd = d; bnidx = j * 512 + t; }  // strict >: first index wins (jnp.argmax)
    }
    unsigned long long key =
        ((unsigned long long)__float_as_uint(bd) << 32) | (unsigned)(~bnidx);
#pragma unroll
    for (int m = 1; m < 64; m <<= 1) {
      unsigned long long o = __shfl_xor(key, m, 64);
      key = (o > key) ? o : key;
    }
    if ((t & 63) == 0) red[t >> 6] = key;
    __syncthreads();
    unsigned long long k2 = red[0];
#pragma unroll
    for (int w = 1; w < 8; w++) k2 = (red[w] > k2) ? red[w] : k2;
    int nf = (int)(~(unsigned)(k2 & 0xFFFFFFFFull));
    if ((nf & 511) == t) {
      int j = nf >> 9;
      float vx = 0, vy = 0, vz = 0;
#pragma unroll
      for (int j2 = 0; j2 < 16; j2++) {  // static indices only (no reg-array scratch)
        if (j2 == j) { vx = px[j2]; vy = py[j2]; vz = pz[j2]; }
      }
      cs[0] = vx; cs[1] = vy; cs[2] = vz;
    }
    __syncthreads();
  }
}

// ---------------- brute-force 32-NN (sorted ascending) ----------------
__global__ __launch_bounds__(128) void knn_kernel(const float4* __restrict__ xyzT,
                                                  const float4* __restrict__ newxyz,
                                                  int* __restrict__ knn) {
  int q = blockIdx.x * 128 + threadIdx.x;  // B*S total
  int b = q >> 10;                         // /Sc
  float4 qv = newxyz[q];
  __shared__ float4 tile[128];
  __shared__ float ld[128 * 33];
  __shared__ int li[128 * 33];
  float* myd = ld + threadIdx.x * 33;
  int* myi = li + threadIdx.x * 33;
  const float4* pb = xyzT + (size_t)b * Nc;
  int cnt = 0;
  float worst = 1e30f;
  for (int t0 = 0; t0 < Nc; t0 += 128) {
    __syncthreads();
    tile[threadIdx.x] = pb[t0 + threadIdx.x];
    __syncthreads();
    for (int u = 0; u < 128; u++) {
      float4 p = tile[u];
      float dot = fmaf(qv.z, p.z, fmaf(qv.y, p.y, qv.x * p.x));
      float d = fmaf(-2.f, dot, qv.w + p.w);  // aa + bb - 2ab, same as reference
      if (d < worst) {                        // strict <: earlier index wins ties
        int j = (cnt < 32) ? cnt : 31;
        while (j > 0 && myd[j - 1] > d) {     // stable: equal keys keep earlier first
          myd[j] = myd[j - 1];
          myi[j] = myi[j - 1];
          j--;
        }
        myd[j] = d;
        myi[j] = t0 + u;
        if (cnt < 32) {
          cnt++;
          if (cnt == 32) worst = myd[31];
        } else {
          worst = myd[31];
        }
      }
    }
  }
#pragma unroll
  for (int k = 0; k < 32; k++) knn[(size_t)q * 32 + k] = myi[k];
}

// ---------------- weight transpose [o][c] -> [c][o] ----------------
__global__ __launch_bounds__(256) void wtrans_kernel(const float* __restrict__ w,
                                                     float* __restrict__ wT, int CO, int CI) {
  int i = blockIdx.x * 256 + threadIdx.x;
  if (i >= CO * CI) return;
  int o = i / CI, c = i % CI;
  wT[c * CO + o] = w[i];
}

// ---------------- P = W_pts . points + bias  -> [B][N][64] ----------------
__global__ __launch_bounds__(256) void pproj_kernel(const float* __restrict__ pts,
                                                    const float* __restrict__ wT0,
                                                    const float* __restrict__ bias,
                                                    float* __restrict__ P) {
  int i = blockIdx.x * 256 + threadIdx.x;  // b*N+n
  int b = i >> 13, n = i & 8191;
  const float* pb = pts + (size_t)b * CINc * Nc + n;
  float acc[64];
#pragma unroll
  for (int o = 0; o < 64; o++) acc[o] = bias[o];
  for (int c = 0; c < CINc; c++) {
    float xv = pb[(size_t)c * Nc];
    const float* wr = wT0 + (3 + c) * 64;
#pragma unroll
    for (int o = 0; o < 64; o++) acc[o] = fmaf(wr[o], xv, acc[o]);
  }
  float4* Pn = (float4*)(P + (size_t)i * 64);
#pragma unroll
  for (int o4 = 0; o4 < 16; o4++)
    Pn[o4] = make_float4(acc[4 * o4], acc[4 * o4 + 1], acc[4 * o4 + 2], acc[4 * o4 + 3]);
}

// ---------------- layer1: gather + xyz part ----------------
__global__ __launch_bounds__(256) void conv1_kernel(const float4* __restrict__ xyzT,
                                                    const float4* __restrict__ newxyz,
                                                    const int* __restrict__ knn,
                                                    const float* __restrict__ P,
                                                    const float* __restrict__ wT0,
                                                    float* __restrict__ y, int K, int Pos) {
  int gp = blockIdx.x * 256 + threadIdx.x;
  int b = gp / Pos, r = gp % Pos;
  int s = r / K, kk = r % K;
  int n = knn[((size_t)(b * Sc + s)) * 32 + kk];
  float4 c4 = newxyz[b * Sc + s];
  float4 p4 = xyzT[(size_t)b * Nc + n];
  float dx = p4.x - c4.x, dy = p4.y - c4.y, dz = p4.z - c4.z;
  const float4* Pn = (const float4*)(P + ((size_t)b * Nc + n) * 64);
  float acc[64];
#pragma unroll
  for (int o4 = 0; o4 < 16; o4++) {
    float4 v = Pn[o4];
    acc[4 * o4] = v.x; acc[4 * o4 + 1] = v.y; acc[4 * o4 + 2] = v.z; acc[4 * o4 + 3] = v.w;
  }
#pragma unroll
  for (int o = 0; o < 64; o++) acc[o] = fmaf(wT0[o], dx, acc[o]);
#pragma unroll
  for (int o = 0; o < 64; o++) acc[o] = fmaf(wT0[64 + o], dy, acc[o]);
#pragma unroll
  for (int o = 0; o < 64; o++) acc[o] = fmaf(wT0[128 + o], dz, acc[o]);
  float* yb = y + (size_t)b * 64 * Pos + r;
#pragma unroll
  for (int o = 0; o < 64; o++) yb[(size_t)o * Pos] = acc[o];
}

// ---------------- per-channel sum / sumsq partials (deterministic) ----------------
__global__ __launch_bounds__(256) void stats_kernel(const float* __restrict__ y,
                                                    float* __restrict__ part, int C, int Pos) {
  int c = blockIdx.x, pt = blockIdx.y;
  int total = Bc * Pos;
  int chunk = total / 16;
  int per = chunk / 256;
  float sum = 0.f, sq = 0.f;
  int base = pt * chunk;
  for (int i2 = 0; i2 < per; i2++) {
    int e = base + i2 * 256 + threadIdx.x;
    int bb = e / Pos, pp = e % Pos;
    float v = y[((size_t)bb * C + c) * Pos + pp];
    sum += v;
    sq = fmaf(v, v, sq);
  }
#pragma unroll
  for (int m = 1; m < 64; m <<= 1) {
    sum += __shfl_xor(sum, m, 64);
    sq += __shfl_xor(sq, m, 64);
  }
  __shared__ float ls[8];
  int w = threadIdx.x >> 6;
  if ((threadIdx.x & 63) == 0) { ls[w] = sum; ls[4 + w] = sq; }
  __syncthreads();
  if (threadIdx.x == 0) {
    float s2 = ls[0] + ls[1] + ls[2] + ls[3];
    float q2 = ls[4] + ls[5] + ls[6] + ls[7];
    part[(c * 16 + pt) * 2] = s2;
    part[(c * 16 + pt) * 2 + 1] = q2;
  }
}

__global__ __launch_bounds__(128) void bnfin_kernel(const float* __restrict__ part,
                                                    const float* __restrict__ g,
                                                    const float* __restrict__ be,
                                                    float* __restrict__ bn, int C, float invcnt) {
  int c = threadIdx.x;
  if (c >= C) return;
  float s = 0.f, q = 0.f;
  for (int p2 = 0; p2 < 16; p2++) {
    s += part[(c * 16 + p2) * 2];
    q += part[(c * 16 + p2) * 2 + 1];
  }
  float m = s * invcnt;
  float v = q * invcnt - m * m;
  float sc = g[c] / sqrtf(v + BN_EPS);
  bn[c * 2] = sc;
  bn[c * 2 + 1] = fmaf(-m, sc, be[c]);
}

// ---------------- mid layer: BN+ReLU on the fly, matmul ----------------
template <int CI, int CO>
__global__ __launch_bounds__(256) void conv2_kernel(const float* __restrict__ yin,
                                                    const float* __restrict__ wT,
                                                    const float* __restrict__ bias,
                                                    const float* __restrict__ bn,
                                                    float* __restrict__ yout, int Pos) {
  int gp = blockIdx.x * 256 + threadIdx.x;
  int b = gp / Pos, r = gp % Pos;
  const float* xin = yin + (size_t)b * CI * Pos + r;
  float acc[CO];
#pragma unroll
  for (int o = 0; o < CO; o++) acc[o] = bias[o];
  for (int c = 0; c < CI; c++) {
    float xv = xin[(size_t)c * Pos];
    xv = fmaxf(fmaf(xv, bn[2 * c], bn[2 * c + 1]), 0.f);
    const float* wr = wT + c * CO;
#pragma unroll
    for (int o = 0; o < CO; o++) acc[o] = fmaf(wr[o], xv, acc[o]);
  }
  float* yo = yout + (size_t)b * CO * Pos + r;
#pragma unroll
  for (int o = 0; o < CO; o++) yo[(size_t)o * Pos] = acc[o];
}

// ---------------- last layer: matmul + per-k max/min + stats, no y2 store ----------------
template <int CI, int K>
__global__ __launch_bounds__(256) void conv3_kernel(const float* __restrict__ yin,
                                                    const float* __restrict__ wT,
                                                    const float* __restrict__ bias,
                                                    const float* __restrict__ bn,
                                                    float* __restrict__ ymax,
                                                    float* __restrict__ ymin,
                                                    float* __restrict__ part, int Pos) {
  constexpr int CO = 128;
  int gp = blockIdx.x * 256 + threadIdx.x;
  int b = gp / Pos, r = gp % Pos;
  int s = r / K;
  const float* xin = yin + (size_t)b * CI * Pos + r;
  float acc[CO];
#pragma unroll
  for (int o = 0; o < CO; o++) acc[o] = bias[o];
  for (int c = 0; c < CI; c++) {
    float xv = xin[(size_t)c * Pos];
    xv = fmaxf(fmaf(xv, bn[2 * c], bn[2 * c + 1]), 0.f);
    const float* wr = wT + c * CO;
#pragma unroll
    for (int o = 0; o < CO; o++) acc[o] = fmaf(wr[o], xv, acc[o]);
  }
  __shared__ float wsum[4][CO];
  __shared__ float wsq[4][CO];
  int lane = threadIdx.x & 63, w = threadIdx.x >> 6;
  bool lead = (r & (K - 1)) == 0;
#pragma unroll
  for (int o = 0; o < CO; o++) {
    float v = acc[o];
    float a = v, bmin = v;
#pragma unroll
    for (int m = 1; m < K; m <<= 1) {
      a = fmaxf(a, __shfl_xor(a, m, K));
      bmin = fminf(bmin, __shfl_xor(bmin, m, K));
    }
    if (lead) {
      ymax[((size_t)b * CO + o) * Sc + s] = a;
      ymin[((size_t)b * CO + o) * Sc + s] = bmin;
    }
    float su = v, qq = v * v;
#pragma unroll
    for (int m = 1; m < 64; m <<= 1) {
      su += __shfl_xor(su, m, 64);
      qq += __shfl_xor(qq, m, 64);
    }
    if (lane == (o & 63)) { wsum[w][o] = su; wsq[w][o] = qq; }
  }
  __syncthreads();
  if (threadIdx.x < CO) {
    int o = threadIdx.x;
    float su = wsum[0][o] + wsum[1][o] + wsum[2][o] + wsum[3][o];
    float qq = wsq[0][o] + wsq[1][o] + wsq[2][o] + wsq[3][o];
    part[((size_t)blockIdx.x * CO + o) * 2] = su;
    part[((size_t)blockIdx.x * CO + o) * 2 + 1] = qq;
  }
}

__global__ __launch_bounds__(256) void bnfin3_kernel(const float* __restrict__ part,
                                                     const float* __restrict__ g,
                                                     const float* __restrict__ be,
                                                     float* __restrict__ bn, int nblk,
                                                     float invcnt) {
  int o = blockIdx.x;
  float s = 0.f, q = 0.f;
  for (int i2 = threadIdx.x; i2 < nblk; i2 += 256) {
    s += part[((size_t)i2 * 128 + o) * 2];
    q += part[((size_t)i2 * 128 + o) * 2 + 1];
  }
#pragma unroll
  for (int m = 1; m < 64; m <<= 1) {
    s += __shfl_xor(s, m, 64);
    q += __shfl_xor(q, m, 64);
  }
  __shared__ float ls[8];
  if ((threadIdx.x & 63) == 0) {
    ls[threadIdx.x >> 6] = s;
    ls[4 + (threadIdx.x >> 6)] = q;
  }
  __syncthreads();
  if (threadIdx.x == 0) {
    float ss = ls[0] + ls[1] + ls[2] + ls[3];
    float qq = ls[4] + ls[5] + ls[6] + ls[7];
    float m = ss * invcnt;
    float v = qq * invcnt - m * m;
    float sc = g[o] / sqrtf(v + BN_EPS);
    bn[o * 2] = sc;
    bn[o * 2 + 1] = fmaf(-m, sc, be[o]);
  }
}

__global__ __launch_bounds__(256) void finout_kernel(const float* __restrict__ ymax,
                                                     const float* __restrict__ ymin,
                                                     const float* __restrict__ bn,
                                                     float* __restrict__ out1, int coff) {
  int i = blockIdx.x * 256 + threadIdx.x;  // B*128*S
  int b = i / (128 * Sc);
  int rest = i % (128 * Sc);
  int o = rest / Sc, s = rest % Sc;
  float sc = bn[o * 2], sh = bn[o * 2 + 1];
  float v = (sc >= 0.f) ? ymax[i] : ymin[i];  // ReLU∘affine is monotone; max over k
  out1[((size_t)b * 256 + coff + o) * Sc + s] = fmaxf(fmaf(v, sc, sh), 0.f);
}

extern "C" void kernel_launch(void* const* d_in, const int* in_sizes, int n_in,
                              void* d_out, int out_size, void* d_ws, size_t ws_size,
                              hipStream_t stream) {
  const float* xyz = (const float*)d_in[0];
  const float* pts = (const float*)d_in[1];
  float* ws = (float*)d_ws;
  float* out0 = (float*)d_out;
  float* out1 = out0 + Bc * 3 * Sc;

  float4* xyzT = (float4*)(ws + 0);
  float4* nx = (float4*)(ws + 262144);
  int* knn = (int*)(ws + 294912);
  float* P = ws + 557056;
  float* y0 = ws + 4751360;
  float* y1 = ws + 21528576;
  float* ymax = ws + 46694400;
  float* ymin = ws + 47742976;
  float* part = ws + 48791552;
  float* wT0 = ws + 49053696;
  float* wT2 = ws + 49058048;
  float* wT3 = ws + 49064192;
  float* bn1 = ws + 49076480;
  float* bn2 = ws + 49076608;
  float* bn3 = ws + 49076800;

  xyzt_kernel<<<(Bc * Nc) / 256, 256, 0, stream>>>(xyz, xyzT);
  fps_kernel<<<Bc, 512, 0, stream>>>(xyz, nx, out0);
  knn_kernel<<<(Bc * Sc) / 128, 128, 0, stream>>>(xyzT, nx, knn);

  for (int br = 0; br < 2; br++) {
    int base = 2 + br * 12;
    const float* w0 = (const float*)d_in[base + 0];
    const float* b0 = (const float*)d_in[base + 1];
    const float* g0 = (const float*)d_in[base + 2];
    const float* be0 = (const float*)d_in[base + 3];
    const float* w1 = (const float*)d_in[base + 4];
    const float* b1 = (const float*)d_in[base + 5];
    const float* g1 = (const float*)d_in[base + 6];
    const float* be1 = (const float*)d_in[base + 7];
    const float* w2 = (const float*)d_in[base + 8];
    const float* b2 = (const float*)d_in[base + 9];
    const float* g2 = (const float*)d_in[base + 10];
    const float* be2 = (const float*)d_in[base + 11];
    int K = br ? 32 : 16;
    int Pos = Sc * K;
    int CO2 = br ? 96 : 64;
    float invcnt = 1.f / (float)(Bc * Pos);
    int nblk = (Bc * Pos) / 256;

    wtrans_kernel<<<(67 * 64 + 255) / 256, 256, 0, stream>>>(w0, wT0, 64, 67);
    pproj_kernel<<<(Bc * Nc) / 256, 256, 0, stream>>>(pts, wT0, b0, P);
    conv1_kernel<<<(Bc * Pos) / 256, 256, 0, stream>>>(xyzT, nx, knn, P, wT0, y0, K, Pos);
    stats_kernel<<<dim3(64, 16), 256, 0, stream>>>(y0, part, 64, Pos);
    bnfin_kernel<<<1, 128, 0, stream>>>(part, g0, be0, bn1, 64, invcnt);

    wtrans_kernel<<<(CO2 * 64 + 255) / 256, 256, 0, stream>>>(w1, wT2, CO2, 64);
    if (br == 0)
      conv2_kernel<64, 64><<<(Bc * Pos) / 256, 256, 0, stream>>>(y0, wT2, b1, bn1, y1, Pos);
    else
      conv2_kernel<64, 96><<<(Bc * Pos) / 256, 256, 0, stream>>>(y0, wT2, b1, bn1, y1, Pos);
    stats_kernel<<<dim3(CO2, 16), 256, 0, stream>>>(y1, part, CO2, Pos);
    bnfin_kernel<<<1, 128, 0, stream>>>(part, g1, be1, bn2, CO2, invcnt);

    wtrans_kernel<<<(128 * CO2 + 255) / 256, 256, 0, stream>>>(w2, wT3, 128, CO2);
    if (br == 0)
      conv3_kernel<64, 16><<<(Bc * Pos) / 256, 256, 0, stream>>>(y1, wT3, b2, bn2, ymax, ymin,
                                                                 part, Pos);
    else
      conv3_kernel<96, 32><<<(Bc * Pos) / 256, 256, 0, stream>>>(y1, wT3, b2, bn2, ymax, ymin,
                                                                 part, Pos);
    bnfin3_kernel<<<128, 256, 0, stream>>>(part, g2, be2, bn3, nblk, invcnt);
    finout_kernel<<<(Bc * 128 * Sc) / 256, 256, 0, stream>>>(ymax, ymin, bn3, out1, br * 128);
  }
  (void)in_sizes; (void)n_in; (void)out_size; (void)ws_size;
}

// Round 2
// 2385.667 us; speedup vs baseline: 4.4011x; 4.4011x over previous
//
#include <hip/hip_runtime.h>
#include <math.h>

#define BN_EPS 1e-5f
constexpr int Bc = 8, Nc = 8192, Sc = 1024, CINc = 64;

// ---------------- xyz transpose + |p|^2 ----------------
__global__ __launch_bounds__(256) void xyzt_kernel(const float* __restrict__ xyz,
                                                   float4* __restrict__ xyzT) {
  int i = blockIdx.x * 256 + threadIdx.x;
  if (i >= Bc * Nc) return;
  int b = i / Nc, n = i % Nc;
  const float* xb = xyz + (size_t)b * 3 * Nc;
  float x = xb[n], y = xb[Nc + n], z = xb[2 * Nc + n];
  xyzT[i] = make_float4(x, y, z, fmaf(z, z, fmaf(y, y, x * x)));
}

// ---------------- farthest point sampling ----------------
__global__ __launch_bounds__(512) void fps_kernel(const float* __restrict__ xyz,
                                                  float4* __restrict__ newxyz,
                                                  float* __restrict__ out0) {
  int b = blockIdx.x, t = threadIdx.x;
  const float* xb = xyz + (size_t)b * 3 * Nc;
  float px[16], py[16], pz[16], dd[16];
#pragma unroll
  for (int j = 0; j < 16; j++) {
    int n = j * 512 + t;
    px[j] = xb[n];
    py[j] = xb[Nc + n];
    pz[j] = xb[2 * Nc + n];
    dd[j] = 1e10f;
  }
  __shared__ float cs[3];
  __shared__ unsigned long long red[8];
  if (t == 0) { cs[0] = xb[0]; cs[1] = xb[Nc]; cs[2] = xb[2 * Nc]; }
  __syncthreads();
  for (int i = 0; i < Sc; i++) {
    float cx = cs[0], cy = cs[1], cz = cs[2];
    if (t == 0) {
      newxyz[b * Sc + i] = make_float4(cx, cy, cz, fmaf(cz, cz, fmaf(cy, cy, cx * cx)));
      float* ob = out0 + (size_t)b * 3 * Sc;
      ob[i] = cx; ob[Sc + i] = cy; ob[2 * Sc + i] = cz;
    }
    float bd = -1.f;
    int bnidx = 0;
#pragma unroll
    for (int j = 0; j < 16; j++) {
      float dx = px[j] - cx, dy = py[j] - cy, dz = pz[j] - cz;
      float d = fmaf(dz, dz, fmaf(dy, dy, dx * dx));
      d = fminf(dd[j], d);
      dd[j] = d;
      if (d > bd) { bd = d; bnidx = j * 512 + t; }  // strict >: first index wins (jnp.argmax)
    }
    unsigned long long key =
        ((unsigned long long)__float_as_uint(bd) << 32) | (unsigned)(~bnidx);
#pragma unroll
    for (int m = 1; m < 64; m <<= 1) {
      unsigned long long o = __shfl_xor(key, m, 64);
      key = (o > key) ? o : key;
    }
    if ((t & 63) == 0) red[t >> 6] = key;
    __syncthreads();
    unsigned long long k2 = red[0];
#pragma unroll
    for (int w = 1; w < 8; w++) k2 = (red[w] > k2) ? red[w] : k2;
    int nf = (int)(~(unsigned)(k2 & 0xFFFFFFFFull));
    if ((nf & 511) == t) {
      int j = nf >> 9;
      float vx = 0, vy = 0, vz = 0;
#pragma unroll
      for (int j2 = 0; j2 < 16; j2++) {  // static indices only (no reg-array scratch)
        if (j2 == j) { vx = px[j2]; vy = py[j2]; vz = pz[j2]; }
      }
      cs[0] = vx; cs[1] = vy; cs[2] = vz;
    }
    __syncthreads();
  }
}

// ---------------- wave-cooperative 32-NN ----------------
// Each 32-lane half-wave owns one query; the sorted top-32 list lives ACROSS
// lanes as u64 keys (ordered-float dist << 32 | idx). Lexicographic u64 order
// == (smaller dist, then smaller idx) == lax.top_k tie semantics.
__global__ __launch_bounds__(256) void knn_kernel(const float4* __restrict__ xyzT,
                                                  const float4* __restrict__ newxyz,
                                                  int* __restrict__ knn) {
  int lane = threadIdx.x & 63;
  int sub = lane >> 5;      // half-wave id within wave
  int l32 = lane & 31;      // lane within 32-group
  int waveId = blockIdx.x * 4 + (threadIdx.x >> 6);
  int q = waveId * 2 + sub;  // B*S = 8192 queries
  int b = q >> 10;
  float4 qv = newxyz[q];
  const float4* pb = xyzT + (size_t)b * Nc;
  unsigned long long lk = ~0ull;  // list key held by this lane (sorted asc across lanes)
  for (int t0 = 0; t0 < Nc; t0 += 32) {
    float4 p = pb[t0 + l32];
    float dot = fmaf(qv.z, p.z, fmaf(qv.y, p.y, qv.x * p.x));
    float d = fmaf(-2.f, dot, qv.w + p.w);  // aa + bb - 2ab, same as reference
    unsigned fu = __float_as_uint(d);
    fu ^= (unsigned)(-(int)(fu >> 31)) | 0x80000000u;  // ordered-uint transform
    unsigned long long ck = ((unsigned long long)fu << 32) | (unsigned)(t0 + l32);
    unsigned long long worst = __shfl(lk, 31, 32);
    unsigned long long bal = __ballot(ck < worst);
    if (((unsigned)(bal >> (sub * 32))) == 0u) continue;  // no candidate beats list max
    // bitonic sort of the 32 candidates, ascending across the 32-group
#pragma unroll
    for (int k = 2; k <= 32; k <<= 1) {
#pragma unroll
      for (int j = k >> 1; j > 0; j >>= 1) {
        unsigned long long o = __shfl_xor(ck, j, 32);
        bool up = ((l32 & k) == 0);
        bool lower = ((l32 & j) == 0);
        unsigned long long mn = (o < ck) ? o : ck;
        unsigned long long mx = (o < ck) ? ck : o;
        ck = (up == lower) ? mn : mx;
      }
    }
    // keep 32 smallest of (list, cand): L[i] = min(A[i], B[31-i]) is bitonic
    unsigned long long rev = __shfl(ck, 31 - l32, 32);
    unsigned long long m0 = (rev < lk) ? rev : lk;
#pragma unroll
    for (int j = 16; j > 0; j >>= 1) {
      unsigned long long o = __shfl_xor(m0, j, 32);
      bool lower = ((l32 & j) == 0);
      unsigned long long mn = (o < m0) ? o : m0;
      unsigned long long mx = (o < m0) ? m0 : o;
      m0 = lower ? mn : mx;
    }
    lk = m0;
  }
  knn[(size_t)q * 32 + l32] = (int)(lk & 0xFFFFFFFFu);
}

// ---------------- weight transpose [o][c] -> [c][o] ----------------
__global__ __launch_bounds__(256) void wtrans_kernel(const float* __restrict__ w,
                                                     float* __restrict__ wT, int CO, int CI) {
  int i = blockIdx.x * 256 + threadIdx.x;
  if (i >= CO * CI) return;
  int o = i / CI, c = i % CI;
  wT[c * CO + o] = w[i];
}

// ---------------- P = W_pts . points + bias  -> [B][N][64] ----------------
__global__ __launch_bounds__(256) void pproj_kernel(const float* __restrict__ pts,
                                                    const float* __restrict__ wT0,
                                                    const float* __restrict__ bias,
                                                    float* __restrict__ P) {
  int i = blockIdx.x * 256 + threadIdx.x;  // b*N+n
  int b = i >> 13, n = i & 8191;
  const float* pb = pts + (size_t)b * CINc * Nc + n;
  float acc[64];
#pragma unroll
  for (int o = 0; o < 64; o++) acc[o] = bias[o];
  for (int c = 0; c < CINc; c++) {
    float xv = pb[(size_t)c * Nc];
    const float* wr = wT0 + (3 + c) * 64;
#pragma unroll
    for (int o = 0; o < 64; o++) acc[o] = fmaf(wr[o], xv, acc[o]);
  }
  float4* Pn = (float4*)(P + (size_t)i * 64);
#pragma unroll
  for (int o4 = 0; o4 < 16; o4++)
    Pn[o4] = make_float4(acc[4 * o4], acc[4 * o4 + 1], acc[4 * o4 + 2], acc[4 * o4 + 3]);
}

// ---------------- layer1: gather + xyz part ----------------
__global__ __launch_bounds__(256) void conv1_kernel(const float4* __restrict__ xyzT,
                                                    const float4* __restrict__ newxyz,
                                                    const int* __restrict__ knn,
                                                    const float* __restrict__ P,
                                                    const float* __restrict__ wT0,
                                                    float* __restrict__ y, int K, int Pos) {
  int gp = blockIdx.x * 256 + threadIdx.x;
  int b = gp / Pos, r = gp % Pos;
  int s = r / K, kk = r % K;
  int n = knn[((size_t)(b * Sc + s)) * 32 + kk];
  float4 c4 = newxyz[b * Sc + s];
  float4 p4 = xyzT[(size_t)b * Nc + n];
  float dx = p4.x - c4.x, dy = p4.y - c4.y, dz = p4.z - c4.z;
  const float4* Pn = (const float4*)(P + ((size_t)b * Nc + n) * 64);
  float acc[64];
#pragma unroll
  for (int o4 = 0; o4 < 16; o4++) {
    float4 v = Pn[o4];
    acc[4 * o4] = v.x; acc[4 * o4 + 1] = v.y; acc[4 * o4 + 2] = v.z; acc[4 * o4 + 3] = v.w;
  }
#pragma unroll
  for (int o = 0; o < 64; o++) acc[o] = fmaf(wT0[o], dx, acc[o]);
#pragma unroll
  for (int o = 0; o < 64; o++) acc[o] = fmaf(wT0[64 + o], dy, acc[o]);
#pragma unroll
  for (int o = 0; o < 64; o++) acc[o] = fmaf(wT0[128 + o], dz, acc[o]);
  float* yb = y + (size_t)b * 64 * Pos + r;
#pragma unroll
  for (int o = 0; o < 64; o++) yb[(size_t)o * Pos] = acc[o];
}

// ---------------- per-channel sum / sumsq partials (deterministic) ----------------
__global__ __launch_bounds__(256) void stats_kernel(const float* __restrict__ y,
                                                    float* __restrict__ part, int C, int Pos) {
  int c = blockIdx.x, pt = blockIdx.y;
  int total = Bc * Pos;
  int chunk = total / 16;
  int per = chunk / 256;
  float sum = 0.f, sq = 0.f;
  int base = pt * chunk;
  for (int i2 = 0; i2 < per; i2++) {
    int e = base + i2 * 256 + threadIdx.x;
    int bb = e / Pos, pp = e % Pos;
    float v = y[((size_t)bb * C + c) * Pos + pp];
    sum += v;
    sq = fmaf(v, v, sq);
  }
#pragma unroll
  for (int m = 1; m < 64; m <<= 1) {
    sum += __shfl_xor(sum, m, 64);
    sq += __shfl_xor(sq, m, 64);
  }
  __shared__ float ls[8];
  int w = threadIdx.x >> 6;
  if ((threadIdx.x & 63) == 0) { ls[w] = sum; ls[4 + w] = sq; }
  __syncthreads();
  if (threadIdx.x == 0) {
    float s2 = ls[0] + ls[1] + ls[2] + ls[3];
    float q2 = ls[4] + ls[5] + ls[6] + ls[7];
    part[(c * 16 + pt) * 2] = s2;
    part[(c * 16 + pt) * 2 + 1] = q2;
  }
}

__global__ __launch_bounds__(128) void bnfin_kernel(const float* __restrict__ part,
                                                    const float* __restrict__ g,
                                                    const float* __restrict__ be,
                                                    float* __restrict__ bn, int C, float invcnt) {
  int c = threadIdx.x;
  if (c >= C) return;
  float s = 0.f, q = 0.f;
  for (int p2 = 0; p2 < 16; p2++) {
    s += part[(c * 16 + p2) * 2];
    q += part[(c * 16 + p2) * 2 + 1];
  }
  float m = s * invcnt;
  float v = q * invcnt - m * m;
  float sc = g[c] / sqrtf(v + BN_EPS);
  bn[c * 2] = sc;
  bn[c * 2 + 1] = fmaf(-m, sc, be[c]);
}

// ---------------- mid layer: BN+ReLU on the fly, matmul ----------------
template <int CI, int CO>
__global__ __launch_bounds__(256) void conv2_kernel(const float* __restrict__ yin,
                                                    const float* __restrict__ wT,
                                                    const float* __restrict__ bias,
                                                    const float* __restrict__ bn,
                                                    float* __restrict__ yout, int Pos) {
  int gp = blockIdx.x * 256 + threadIdx.x;
  int b = gp / Pos, r = gp % Pos;
  const float* xin = yin + (size_t)b * CI * Pos + r;
  float acc[CO];
#pragma unroll
  for (int o = 0; o < CO; o++) acc[o] = bias[o];
  for (int c = 0; c < CI; c++) {
    float xv = xin[(size_t)c * Pos];
    xv = fmaxf(fmaf(xv, bn[2 * c], bn[2 * c + 1]), 0.f);
    const float* wr = wT + c * CO;
#pragma unroll
    for (int o = 0; o < CO; o++) acc[o] = fmaf(wr[o], xv, acc[o]);
  }
  float* yo = yout + (size_t)b * CO * Pos + r;
#pragma unroll
  for (int o = 0; o < CO; o++) yo[(size_t)o * Pos] = acc[o];
}

// ---------------- last layer: matmul + per-k max/min + stats, no y2 store ----------------
template <int CI, int K>
__global__ __launch_bounds__(256) void conv3_kernel(const float* __restrict__ yin,
                                                    const float* __restrict__ wT,
                                                    const float* __restrict__ bias,
                                                    const float* __restrict__ bn,
                                                    float* __restrict__ ymax,
                                                    float* __restrict__ ymin,
                                                    float* __restrict__ part, int Pos) {
  constexpr int CO = 128;
  int gp = blockIdx.x * 256 + threadIdx.x;
  int b = gp / Pos, r = gp % Pos;
  int s = r / K;
  const float* xin = yin + (size_t)b * CI * Pos + r;
  float acc[CO];
#pragma unroll
  for (int o = 0; o < CO; o++) acc[o] = bias[o];
  for (int c = 0; c < CI; c++) {
    float xv = xin[(size_t)c * Pos];
    xv = fmaxf(fmaf(xv, bn[2 * c], bn[2 * c + 1]), 0.f);
    const float* wr = wT + c * CO;
#pragma unroll
    for (int o = 0; o < CO; o++) acc[o] = fmaf(wr[o], xv, acc[o]);
  }
  __shared__ float wsum[4][CO];
  __shared__ float wsq[4][CO];
  int lane = threadIdx.x & 63, w = threadIdx.x >> 6;
  bool lead = (r & (K - 1)) == 0;
#pragma unroll
  for (int o = 0; o < CO; o++) {
    float v = acc[o];
    float a = v, bmin = v;
#pragma unroll
    for (int m = 1; m < K; m <<= 1) {
      a = fmaxf(a, __shfl_xor(a, m, K));
      bmin = fminf(bmin, __shfl_xor(bmin, m, K));
    }
    if (lead) {
      ymax[((size_t)b * CO + o) * Sc + s] = a;
      ymin[((size_t)b * CO + o) * Sc + s] = bmin;
    }
    float su = v, qq = v * v;
#pragma unroll
    for (int m = 1; m < 64; m <<= 1) {
      su += __shfl_xor(su, m, 64);
      qq += __shfl_xor(qq, m, 64);
    }
    if (lane == (o & 63)) { wsum[w][o] = su; wsq[w][o] = qq; }
  }
  __syncthreads();
  if (threadIdx.x < CO) {
    int o = threadIdx.x;
    float su = wsum[0][o] + wsum[1][o] + wsum[2][o] + wsum[3][o];
    float qq = wsq[0][o] + wsq[1][o] + wsq[2][o] + wsq[3][o];
    part[((size_t)blockIdx.x * CO + o) * 2] = su;
    part[((size_t)blockIdx.x * CO + o) * 2 + 1] = qq;
  }
}

__global__ __launch_bounds__(256) void bnfin3_kernel(const float* __restrict__ part,
                                                     const float* __restrict__ g,
                                                     const float* __restrict__ be,
                                                     float* __restrict__ bn, int nblk,
                                                     float invcnt) {
  int o = blockIdx.x;
  float s = 0.f, q = 0.f;
  for (int i2 = threadIdx.x; i2 < nblk; i2 += 256) {
    s += part[((size_t)i2 * 128 + o) * 2];
    q += part[((size_t)i2 * 128 + o) * 2 + 1];
  }
#pragma unroll
  for (int m = 1; m < 64; m <<= 1) {
    s += __shfl_xor(s, m, 64);
    q += __shfl_xor(q, m, 64);
  }
  __shared__ float ls[8];
  if ((threadIdx.x & 63) == 0) {
    ls[threadIdx.x >> 6] = s;
    ls[4 + (threadIdx.x >> 6)] = q;
  }
  __syncthreads();
  if (threadIdx.x == 0) {
    float ss = ls[0] + ls[1] + ls[2] + ls[3];
    float qq = ls[4] + ls[5] + ls[6] + ls[7];
    float m = ss * invcnt;
    float v = qq * invcnt - m * m;
    float sc = g[o] / sqrtf(v + BN_EPS);
    bn[o * 2] = sc;
    bn[o * 2 + 1] = fmaf(-m, sc, be[o]);
  }
}

__global__ __launch_bounds__(256) void finout_kernel(const float* __restrict__ ymax,
                                                     const float* __restrict__ ymin,
                                                     const float* __restrict__ bn,
                                                     float* __restrict__ out1, int coff) {
  int i = blockIdx.x * 256 + threadIdx.x;  // B*128*S
  int b = i / (128 * Sc);
  int rest = i % (128 * Sc);
  int o = rest / Sc, s = rest % Sc;
  float sc = bn[o * 2], sh = bn[o * 2 + 1];
  float v = (sc >= 0.f) ? ymax[i] : ymin[i];  // ReLU∘affine is monotone; max over k
  out1[((size_t)b * 256 + coff + o) * Sc + s] = fmaxf(fmaf(v, sc, sh), 0.f);
}

extern "C" void kernel_launch(void* const* d_in, const int* in_sizes, int n_in,
                              void* d_out, int out_size, void* d_ws, size_t ws_size,
                              hipStream_t stream) {
  const float* xyz = (const float*)d_in[0];
  const float* pts = (const float*)d_in[1];
  float* ws = (float*)d_ws;
  float* out0 = (float*)d_out;
  float* out1 = out0 + Bc * 3 * Sc;

  float4* xyzT = (float4*)(ws + 0);
  float4* nx = (float4*)(ws + 262144);
  int* knn = (int*)(ws + 294912);
  float* P = ws + 557056;
  float* y0 = ws + 4751360;
  float* y1 = ws + 21528576;
  float* ymax = ws + 46694400;
  float* ymin = ws + 47742976;
  float* part = ws + 48791552;
  float* wT0 = ws + 49053696;
  float* wT2 = ws + 49058048;
  float* wT3 = ws + 49064192;
  float* bn1 = ws + 49076480;
  float* bn2 = ws + 49076608;
  float* bn3 = ws + 49076800;

  xyzt_kernel<<<(Bc * Nc) / 256, 256, 0, stream>>>(xyz, xyzT);
  fps_kernel<<<Bc, 512, 0, stream>>>(xyz, nx, out0);
  knn_kernel<<<(Bc * Sc) / 8, 256, 0, stream>>>(xyzT, nx, knn);

  for (int br = 0; br < 2; br++) {
    int base = 2 + br * 12;
    const float* w0 = (const float*)d_in[base + 0];
    const float* b0 = (const float*)d_in[base + 1];
    const float* g0 = (const float*)d_in[base + 2];
    const float* be0 = (const float*)d_in[base + 3];
    const float* w1 = (const float*)d_in[base + 4];
    const float* b1 = (const float*)d_in[base + 5];
    const float* g1 = (const float*)d_in[base + 6];
    const float* be1 = (const float*)d_in[base + 7];
    const float* w2 = (const float*)d_in[base + 8];
    const float* b2 = (const float*)d_in[base + 9];
    const float* g2 = (const float*)d_in[base + 10];
    const float* be2 = (const float*)d_in[base + 11];
    int K = br ? 32 : 16;
    int Pos = Sc * K;
    int CO2 = br ? 96 : 64;
    float invcnt = 1.f / (float)(Bc * Pos);
    int nblk = (Bc * Pos) / 256;

    wtrans_kernel<<<(67 * 64 + 255) / 256, 256, 0, stream>>>(w0, wT0, 64, 67);
    pproj_kernel<<<(Bc * Nc) / 256, 256, 0, stream>>>(pts, wT0, b0, P);
    conv1_kernel<<<(Bc * Pos) / 256, 256, 0, stream>>>(xyzT, nx, knn, P, wT0, y0, K, Pos);
    stats_kernel<<<dim3(64, 16), 256, 0, stream>>>(y0, part, 64, Pos);
    bnfin_kernel<<<1, 128, 0, stream>>>(part, g0, be0, bn1, 64, invcnt);

    wtrans_kernel<<<(CO2 * 64 + 255) / 256, 256, 0, stream>>>(w1, wT2, CO2, 64);
    if (br == 0)
      conv2_kernel<64, 64><<<(Bc * Pos) / 256, 256, 0, stream>>>(y0, wT2, b1, bn1, y1, Pos);
    else
      conv2_kernel<64, 96><<<(Bc * Pos) / 256, 256, 0, stream>>>(y0, wT2, b1, bn1, y1, Pos);
    stats_kernel<<<dim3(CO2, 16), 256, 0, stream>>>(y1, part, CO2, Pos);
    bnfin_kernel<<<1, 128, 0, stream>>>(part, g1, be1, bn2, CO2, invcnt);

    wtrans_kernel<<<(128 * CO2 + 255) / 256, 256, 0, stream>>>(w2, wT3, 128, CO2);
    if (br == 0)
      conv3_kernel<64, 16><<<(Bc * Pos) / 256, 256, 0, stream>>>(y1, wT3, b2, bn2, ymax, ymin,
                                                                 part, Pos);
    else
      conv3_kernel<96, 32><<<(Bc * Pos) / 256, 256, 0, stream>>>(y1, wT3, b2, bn2, ymax, ymin,
                                                                 part, Pos);
    bnfin3_kernel<<<128, 256, 0, stream>>>(part, g2, be2, bn3, nblk, invcnt);
    finout_kernel<<<(Bc * 128 * Sc) / 256, 256, 0, stream>>>(ymax, ymin, bn3, out1, br * 128);
  }
  (void)in_sizes; (void)n_in; (void)out_size; (void)ws_size;
}

// Round 3
// 2033.118 us; speedup vs baseline: 5.1642x; 1.1734x over previous
//
#include <hip/hip_runtime.h>
#include <math.h>

#define BN_EPS 1e-5f
constexpr int Bc = 8, Nc = 8192, Sc = 1024, CINc = 64;

// ---------------- xyz transpose + |p|^2 ----------------
__global__ __launch_bounds__(256) void xyzt_kernel(const float* __restrict__ xyz,
                                                   float4* __restrict__ xyzT) {
  int i = blockIdx.x * 256 + threadIdx.x;
  if (i >= Bc * Nc) return;
  int b = i / Nc, n = i % Nc;
  const float* xb = xyz + (size_t)b * 3 * Nc;
  float x = xb[n], y = xb[Nc + n], z = xb[2 * Nc + n];
  xyzT[i] = make_float4(x, y, z, fmaf(z, z, fmaf(y, y, x * x)));
}

// ---------------- farthest point sampling ----------------
// DPP prefix-max within each wave (row_shr 1/2/4/8 + bcast15 + bcast31),
// single barrier per iteration, centroid re-fetched via broadcast global load.
template <int CTRL, int RMASK>
__device__ __forceinline__ unsigned long long dpp_maxstep(unsigned long long k) {
  int lo = (int)(unsigned)k, hi = (int)(unsigned)(k >> 32);
  int olo = __builtin_amdgcn_update_dpp(lo, lo, CTRL, RMASK, 0xF, false);
  int ohi = __builtin_amdgcn_update_dpp(hi, hi, CTRL, RMASK, 0xF, false);
  unsigned long long ok = ((unsigned long long)(unsigned)ohi << 32) | (unsigned)olo;
  return ok > k ? ok : k;
}

__global__ __launch_bounds__(512) void fps_kernel(const float4* __restrict__ xyzT,
                                                  float4* __restrict__ newxyz,
                                                  float* __restrict__ out0) {
  int b = blockIdx.x, t = threadIdx.x;
  const float4* pb = xyzT + (size_t)b * Nc;
  float px[16], py[16], pz[16], dd[16];
#pragma unroll
  for (int j = 0; j < 16; j++) {
    float4 p = pb[j * 512 + t];
    px[j] = p.x; py[j] = p.y; pz[j] = p.z;
    dd[j] = 1e10f;
  }
  __shared__ unsigned long long red[2][8];
  int w = t >> 6;
  int curIdx = 0;
  for (int i = 0; i < Sc; i++) {
    float4 c4 = pb[curIdx];  // 64-lane broadcast load (L2 hit)
    float cx = c4.x, cy = c4.y, cz = c4.z;
    if (t == 0) {
      newxyz[b * Sc + i] = c4;
      float* ob = out0 + (size_t)b * 3 * Sc;
      ob[i] = cx; ob[Sc + i] = cy; ob[2 * Sc + i] = cz;
    }
    float bd = -1.f;
    int bnidx = 0;
#pragma unroll
    for (int j = 0; j < 16; j++) {
      float dx = px[j] - cx, dy = py[j] - cy, dz = pz[j] - cz;
      float d = fmaf(dz, dz, fmaf(dy, dy, dx * dx));
      d = fminf(dd[j], d);
      dd[j] = d;
      if (d > bd) { bd = d; bnidx = j * 512 + t; }  // strict >: first index wins (jnp.argmax)
    }
    unsigned long long key =
        ((unsigned long long)__float_as_uint(bd) << 32) | (unsigned)(~bnidx);
    key = dpp_maxstep<0x111, 0xF>(key);  // row_shr:1
    key = dpp_maxstep<0x112, 0xF>(key);  // row_shr:2
    key = dpp_maxstep<0x114, 0xF>(key);  // row_shr:4
    key = dpp_maxstep<0x118, 0xF>(key);  // row_shr:8
    key = dpp_maxstep<0x142, 0xA>(key);  // row_bcast15 -> rows 1,3
    key = dpp_maxstep<0x143, 0xC>(key);  // row_bcast31 -> rows 2,3
    if ((t & 63) == 63) red[i & 1][w] = key;  // lane 63 holds wave max
    __syncthreads();
    unsigned long long k2 = red[i & 1][0];
#pragma unroll
    for (int u = 1; u < 8; u++) {
      unsigned long long o = red[i & 1][u];
      k2 = (o > k2) ? o : k2;
    }
    curIdx = (int)(~(unsigned)(k2 & 0xFFFFFFFFull));
  }
}

// ---------------- wave-cooperative 32-NN ----------------
// Each 32-lane half-wave owns one query; the sorted top-32 list lives ACROSS
// lanes as u64 keys (ordered-float dist << 32 | idx). Lexicographic u64 order
// == (smaller dist, then smaller idx) == lax.top_k tie semantics.
__global__ __launch_bounds__(256) void knn_kernel(const float4* __restrict__ xyzT,
                                                  const float4* __restrict__ newxyz,
                                                  int* __restrict__ knn) {
  int lane = threadIdx.x & 63;
  int sub = lane >> 5;      // half-wave id within wave
  int l32 = lane & 31;      // lane within 32-group
  int waveId = blockIdx.x * 4 + (threadIdx.x >> 6);
  int q = waveId * 2 + sub;  // B*S = 8192 queries
  int b = q >> 10;
  float4 qv = newxyz[q];
  const float4* pb = xyzT + (size_t)b * Nc;
  unsigned long long lk = ~0ull;  // list key held by this lane (sorted asc across lanes)
  for (int t0 = 0; t0 < Nc; t0 += 32) {
    float4 p = pb[t0 + l32];
    float dot = fmaf(qv.z, p.z, fmaf(qv.y, p.y, qv.x * p.x));
    float d = fmaf(-2.f, dot, qv.w + p.w);  // aa + bb - 2ab, same as reference
    unsigned fu = __float_as_uint(d);
    fu ^= (unsigned)(-(int)(fu >> 31)) | 0x80000000u;  // ordered-uint transform
    unsigned long long ck = ((unsigned long long)fu << 32) | (unsigned)(t0 + l32);
    unsigned long long worst = __shfl(lk, 31, 32);
    unsigned long long bal = __ballot(ck < worst);
    if (((unsigned)(bal >> (sub * 32))) == 0u) continue;  // no candidate beats list max
    // bitonic sort of the 32 candidates, ascending across the 32-group
#pragma unroll
    for (int k = 2; k <= 32; k <<= 1) {
#pragma unroll
      for (int j = k >> 1; j > 0; j >>= 1) {
        unsigned long long o = __shfl_xor(ck, j, 32);
        bool up = ((l32 & k) == 0);
        bool lower = ((l32 & j) == 0);
        unsigned long long mn = (o < ck) ? o : ck;
        unsigned long long mx = (o < ck) ? ck : o;
        ck = (up == lower) ? mn : mx;
      }
    }
    // keep 32 smallest of (list, cand): L[i] = min(A[i], B[31-i]) is bitonic
    unsigned long long rev = __shfl(ck, 31 - l32, 32);
    unsigned long long m0 = (rev < lk) ? rev : lk;
#pragma unroll
    for (int j = 16; j > 0; j >>= 1) {
      unsigned long long o = __shfl_xor(m0, j, 32);
      bool lower = ((l32 & j) == 0);
      unsigned long long mn = (o < m0) ? o : m0;
      unsigned long long mx = (o < m0) ? m0 : o;
      m0 = lower ? mn : mx;
    }
    lk = m0;
  }
  knn[(size_t)q * 32 + l32] = (int)(lk & 0xFFFFFFFFu);
}

// ---------------- weight transpose [o][c] -> [c][o] ----------------
__global__ __launch_bounds__(256) void wtrans_kernel(const float* __restrict__ w,
                                                     float* __restrict__ wT, int CO, int CI) {
  int i = blockIdx.x * 256 + threadIdx.x;
  if (i >= CO * CI) return;
  int o = i / CI, c = i % CI;
  wT[c * CO + o] = w[i];
}

// ---------------- P = W_pts . points + bias  -> [B][N][64] ----------------
__global__ __launch_bounds__(256) void pproj_kernel(const float* __restrict__ pts,
                                                    const float* __restrict__ wT0,
                                                    const float* __restrict__ bias,
                                                    float* __restrict__ P) {
  int i = blockIdx.x * 256 + threadIdx.x;  // b*N+n
  int b = i >> 13, n = i & 8191;
  const float* pb = pts + (size_t)b * CINc * Nc + n;
  float acc[64];
#pragma unroll
  for (int o = 0; o < 64; o++) acc[o] = bias[o];
  for (int c = 0; c < CINc; c++) {
    float xv = pb[(size_t)c * Nc];
    const float* wr = wT0 + (3 + c) * 64;
#pragma unroll
    for (int o = 0; o < 64; o++) acc[o] = fmaf(wr[o], xv, acc[o]);
  }
  float4* Pn = (float4*)(P + (size_t)i * 64);
#pragma unroll
  for (int o4 = 0; o4 < 16; o4++)
    Pn[o4] = make_float4(acc[4 * o4], acc[4 * o4 + 1], acc[4 * o4 + 2], acc[4 * o4 + 3]);
}

// ---------------- layer1: gather + xyz part ----------------
__global__ __launch_bounds__(256) void conv1_kernel(const float4* __restrict__ xyzT,
                                                    const float4* __restrict__ newxyz,
                                                    const int* __restrict__ knn,
                                                    const float* __restrict__ P,
                                                    const float* __restrict__ wT0,
                                                    float* __restrict__ y, int K, int Pos) {
  int gp = blockIdx.x * 256 + threadIdx.x;
  int b = gp / Pos, r = gp % Pos;
  int s = r / K, kk = r % K;
  int n = knn[((size_t)(b * Sc + s)) * 32 + kk];
  float4 c4 = newxyz[b * Sc + s];
  float4 p4 = xyzT[(size_t)b * Nc + n];
  float dx = p4.x - c4.x, dy = p4.y - c4.y, dz = p4.z - c4.z;
  const float4* Pn = (const float4*)(P + ((size_t)b * Nc + n) * 64);
  float acc[64];
#pragma unroll
  for (int o4 = 0; o4 < 16; o4++) {
    float4 v = Pn[o4];
    acc[4 * o4] = v.x; acc[4 * o4 + 1] = v.y; acc[4 * o4 + 2] = v.z; acc[4 * o4 + 3] = v.w;
  }
#pragma unroll
  for (int o = 0; o < 64; o++) acc[o] = fmaf(wT0[o], dx, acc[o]);
#pragma unroll
  for (int o = 0; o < 64; o++) acc[o] = fmaf(wT0[64 + o], dy, acc[o]);
#pragma unroll
  for (int o = 0; o < 64; o++) acc[o] = fmaf(wT0[128 + o], dz, acc[o]);
  float* yb = y + (size_t)b * 64 * Pos + r;
#pragma unroll
  for (int o = 0; o < 64; o++) yb[(size_t)o * Pos] = acc[o];
}

// ---------------- per-channel sum / sumsq partials (deterministic) ----------------
__global__ __launch_bounds__(256) void stats_kernel(const float* __restrict__ y,
                                                    float* __restrict__ part, int C, int Pos) {
  int c = blockIdx.x, pt = blockIdx.y;
  int total = Bc * Pos;
  int chunk = total / 16;
  int per = chunk / 256;
  float sum = 0.f, sq = 0.f;
  int base = pt * chunk;
  for (int i2 = 0; i2 < per; i2++) {
    int e = base + i2 * 256 + threadIdx.x;
    int bb = e / Pos, pp = e % Pos;
    float v = y[((size_t)bb * C + c) * Pos + pp];
    sum += v;
    sq = fmaf(v, v, sq);
  }
#pragma unroll
  for (int m = 1; m < 64; m <<= 1) {
    sum += __shfl_xor(sum, m, 64);
    sq += __shfl_xor(sq, m, 64);
  }
  __shared__ float ls[8];
  int w = threadIdx.x >> 6;
  if ((threadIdx.x & 63) == 0) { ls[w] = sum; ls[4 + w] = sq; }
  __syncthreads();
  if (threadIdx.x == 0) {
    float s2 = ls[0] + ls[1] + ls[2] + ls[3];
    float q2 = ls[4] + ls[5] + ls[6] + ls[7];
    part[(c * 16 + pt) * 2] = s2;
    part[(c * 16 + pt) * 2 + 1] = q2;
  }
}

__global__ __launch_bounds__(128) void bnfin_kernel(const float* __restrict__ part,
                                                    const float* __restrict__ g,
                                                    const float* __restrict__ be,
                                                    float* __restrict__ bn, int C, float invcnt) {
  int c = threadIdx.x;
  if (c >= C) return;
  float s = 0.f, q = 0.f;
  for (int p2 = 0; p2 < 16; p2++) {
    s += part[(c * 16 + p2) * 2];
    q += part[(c * 16 + p2) * 2 + 1];
  }
  float m = s * invcnt;
  float v = q * invcnt - m * m;
  float sc = g[c] / sqrtf(v + BN_EPS);
  bn[c * 2] = sc;
  bn[c * 2 + 1] = fmaf(-m, sc, be[c]);
}

// ---------------- mid layer: BN+ReLU on the fly, matmul ----------------
template <int CI, int CO>
__global__ __launch_bounds__(256) void conv2_kernel(const float* __restrict__ yin,
                                                    const float* __restrict__ wT,
                                                    const float* __restrict__ bias,
                                                    const float* __restrict__ bn,
                                                    float* __restrict__ yout, int Pos) {
  int gp = blockIdx.x * 256 + threadIdx.x;
  int b = gp / Pos, r = gp % Pos;
  const float* xin = yin + (size_t)b * CI * Pos + r;
  float acc[CO];
#pragma unroll
  for (int o = 0; o < CO; o++) acc[o] = bias[o];
  for (int c = 0; c < CI; c++) {
    float xv = xin[(size_t)c * Pos];
    xv = fmaxf(fmaf(xv, bn[2 * c], bn[2 * c + 1]), 0.f);
    const float* wr = wT + c * CO;
#pragma unroll
    for (int o = 0; o < CO; o++) acc[o] = fmaf(wr[o], xv, acc[o]);
  }
  float* yo = yout + (size_t)b * CO * Pos + r;
#pragma unroll
  for (int o = 0; o < CO; o++) yo[(size_t)o * Pos] = acc[o];
}

// ---------------- last layer: matmul + per-k max/min + stats, no y2 store ----------------
template <int CI, int K>
__global__ __launch_bounds__(256) void conv3_kernel(const float* __restrict__ yin,
                                                    const float* __restrict__ wT,
                                                    const float* __restrict__ bias,
                                                    const float* __restrict__ bn,
                                                    float* __restrict__ ymax,
                                                    float* __restrict__ ymin,
                                                    float* __restrict__ part, int Pos) {
  constexpr int CO = 128;
  int gp = blockIdx.x * 256 + threadIdx.x;
  int b = gp / Pos, r = gp % Pos;
  int s = r / K;
  const float* xin = yin + (size_t)b * CI * Pos + r;
  float acc[CO];
#pragma unroll
  for (int o = 0; o < CO; o++) acc[o] = bias[o];
  for (int c = 0; c < CI; c++) {
    float xv = xin[(size_t)c * Pos];
    xv = fmaxf(fmaf(xv, bn[2 * c], bn[2 * c + 1]), 0.f);
    const float* wr = wT + c * CO;
#pragma unroll
    for (int o = 0; o < CO; o++) acc[o] = fmaf(wr[o], xv, acc[o]);
  }
  __shared__ float wsum[4][CO];
  __shared__ float wsq[4][CO];
  int lane = threadIdx.x & 63, w = threadIdx.x >> 6;
  bool lead = (r & (K - 1)) == 0;
#pragma unroll
  for (int o = 0; o < CO; o++) {
    float v = acc[o];
    float a = v, bmin = v;
#pragma unroll
    for (int m = 1; m < K; m <<= 1) {
      a = fmaxf(a, __shfl_xor(a, m, K));
      bmin = fminf(bmin, __shfl_xor(bmin, m, K));
    }
    if (lead) {
      ymax[((size_t)b * CO + o) * Sc + s] = a;
      ymin[((size_t)b * CO + o) * Sc + s] = bmin;
    }
    float su = v, qq = v * v;
#pragma unroll
    for (int m = 1; m < 64; m <<= 1) {
      su += __shfl_xor(su, m, 64);
      qq += __shfl_xor(qq, m, 64);
    }
    if (lane == (o & 63)) { wsum[w][o] = su; wsq[w][o] = qq; }
  }
  __syncthreads();
  if (threadIdx.x < CO) {
    int o = threadIdx.x;
    float su = wsum[0][o] + wsum[1][o] + wsum[2][o] + wsum[3][o];
    float qq = wsq[0][o] + wsq[1][o] + wsq[2][o] + wsq[3][o];
    part[((size_t)blockIdx.x * CO + o) * 2] = su;
    part[((size_t)blockIdx.x * CO + o) * 2 + 1] = qq;
  }
}

__global__ __launch_bounds__(256) void bnfin3_kernel(const float* __restrict__ part,
                                                     const float* __restrict__ g,
                                                     const float* __restrict__ be,
                                                     float* __restrict__ bn, int nblk,
                                                     float invcnt) {
  int o = blockIdx.x;
  float s = 0.f, q = 0.f;
  for (int i2 = threadIdx.x; i2 < nblk; i2 += 256) {
    s += part[((size_t)i2 * 128 + o) * 2];
    q += part[((size_t)i2 * 128 + o) * 2 + 1];
  }
#pragma unroll
  for (int m = 1; m < 64; m <<= 1) {
    s += __shfl_xor(s, m, 64);
    q += __shfl_xor(q, m, 64);
  }
  __shared__ float ls[8];
  if ((threadIdx.x & 63) == 0) {
    ls[threadIdx.x >> 6] = s;
    ls[4 + (threadIdx.x >> 6)] = q;
  }
  __syncthreads();
  if (threadIdx.x == 0) {
    float ss = ls[0] + ls[1] + ls[2] + ls[3];
    float qq = ls[4] + ls[5] + ls[6] + ls[7];
    float m = ss * invcnt;
    float v = qq * invcnt - m * m;
    float sc = g[o] / sqrtf(v + BN_EPS);
    bn[o * 2] = sc;
    bn[o * 2 + 1] = fmaf(-m, sc, be[o]);
  }
}

__global__ __launch_bounds__(256) void finout_kernel(const float* __restrict__ ymax,
                                                     const float* __restrict__ ymin,
                                                     const float* __restrict__ bn,
                                                     float* __restrict__ out1, int coff) {
  int i = blockIdx.x * 256 + threadIdx.x;  // B*128*S
  int b = i / (128 * Sc);
  int rest = i % (128 * Sc);
  int o = rest / Sc, s = rest % Sc;
  float sc = bn[o * 2], sh = bn[o * 2 + 1];
  float v = (sc >= 0.f) ? ymax[i] : ymin[i];  // ReLU∘affine is monotone; max over k
  out1[((size_t)b * 256 + coff + o) * Sc + s] = fmaxf(fmaf(v, sc, sh), 0.f);
}

extern "C" void kernel_launch(void* const* d_in, const int* in_sizes, int n_in,
                              void* d_out, int out_size, void* d_ws, size_t ws_size,
                              hipStream_t stream) {
  const float* xyz = (const float*)d_in[0];
  const float* pts = (const float*)d_in[1];
  float* ws = (float*)d_ws;
  float* out0 = (float*)d_out;
  float* out1 = out0 + Bc * 3 * Sc;

  float4* xyzT = (float4*)(ws + 0);
  float4* nx = (float4*)(ws + 262144);
  int* knn = (int*)(ws + 294912);
  float* P = ws + 557056;
  float* y0 = ws + 4751360;
  float* y1 = ws + 21528576;
  float* ymax = ws + 46694400;
  float* ymin = ws + 47742976;
  float* part = ws + 48791552;
  float* wT0 = ws + 49053696;
  float* wT2 = ws + 49058048;
  float* wT3 = ws + 49064192;
  float* bn1 = ws + 49076480;
  float* bn2 = ws + 49076608;
  float* bn3 = ws + 49076800;

  xyzt_kernel<<<(Bc * Nc) / 256, 256, 0, stream>>>(xyz, xyzT);
  fps_kernel<<<Bc, 512, 0, stream>>>(xyzT, nx, out0);
  knn_kernel<<<(Bc * Sc) / 8, 256, 0, stream>>>(xyzT, nx, knn);

  for (int br = 0; br < 2; br++) {
    int base = 2 + br * 12;
    const float* w0 = (const float*)d_in[base + 0];
    const float* b0 = (const float*)d_in[base + 1];
    const float* g0 = (const float*)d_in[base + 2];
    const float* be0 = (const float*)d_in[base + 3];
    const float* w1 = (const float*)d_in[base + 4];
    const float* b1 = (const float*)d_in[base + 5];
    const float* g1 = (const float*)d_in[base + 6];
    const float* be1 = (const float*)d_in[base + 7];
    const float* w2 = (const float*)d_in[base + 8];
    const float* b2 = (const float*)d_in[base + 9];
    const float* g2 = (const float*)d_in[base + 10];
    const float* be2 = (const float*)d_in[base + 11];
    int K = br ? 32 : 16;
    int Pos = Sc * K;
    int CO2 = br ? 96 : 64;
    float invcnt = 1.f / (float)(Bc * Pos);
    int nblk = (Bc * Pos) / 256;

    wtrans_kernel<<<(67 * 64 + 255) / 256, 256, 0, stream>>>(w0, wT0, 64, 67);
    pproj_kernel<<<(Bc * Nc) / 256, 256, 0, stream>>>(pts, wT0, b0, P);
    conv1_kernel<<<(Bc * Pos) / 256, 256, 0, stream>>>(xyzT, nx, knn, P, wT0, y0, K, Pos);
    stats_kernel<<<dim3(64, 16), 256, 0, stream>>>(y0, part, 64, Pos);
    bnfin_kernel<<<1, 128, 0, stream>>>(part, g0, be0, bn1, 64, invcnt);

    wtrans_kernel<<<(CO2 * 64 + 255) / 256, 256, 0, stream>>>(w1, wT2, CO2, 64);
    if (br == 0)
      conv2_kernel<64, 64><<<(Bc * Pos) / 256, 256, 0, stream>>>(y0, wT2, b1, bn1, y1, Pos);
    else
      conv2_kernel<64, 96><<<(Bc * Pos) / 256, 256, 0, stream>>>(y0, wT2, b1, bn1, y1, Pos);
    stats_kernel<<<dim3(CO2, 16), 256, 0, stream>>>(y1, part, CO2, Pos);
    bnfin_kernel<<<1, 128, 0, stream>>>(part, g1, be1, bn2, CO2, invcnt);

    wtrans_kernel<<<(128 * CO2 + 255) / 256, 256, 0, stream>>>(w2, wT3, 128, CO2);
    if (br == 0)
      conv3_kernel<64, 16><<<(Bc * Pos) / 256, 256, 0, stream>>>(y1, wT3, b2, bn2, ymax, ymin,
                                                                 part, Pos);
    else
      conv3_kernel<96, 32><<<(Bc * Pos) / 256, 256, 0, stream>>>(y1, wT3, b2, bn2, ymax, ymin,
                                                                 part, Pos);
    bnfin3_kernel<<<128, 256, 0, stream>>>(part, g2, be2, bn3, nblk, invcnt);
    finout_kernel<<<(Bc * 128 * Sc) / 256, 256, 0, stream>>>(ymax, ymin, bn3, out1, br * 128);
  }
  (void)in_sizes; (void)n_in; (void)out_size; (void)ws_size;
}